// Round 2
// baseline (819.057 us; speedup 1.0000x reference)
//
#include <hip/hip_runtime.h>

#define N_NODES  80000
#define N_EDGES  1280000
#define N_GRAPHS 512
#define DIM      64
#define NCLS     10
#define NBUCK    1250            // N_NODES / 64

// ---------- CSR build via 64-node buckets ----------
// bucket b covers nodes [b*64, b*64+64); packed edge = src | (dst&63)<<20

__global__ void k_bcount(const int* __restrict__ ei, int* __restrict__ bcnt) {
    int e = blockIdx.x * blockDim.x + threadIdx.x;
    if (e < N_EDGES) atomicAdd(&bcnt[ei[N_EDGES + e] >> 6], 1);
}

// single block: exclusive scan of 1250 bucket counts -> bbase, bcursor
__global__ void k_scanb(const int* __restrict__ bcnt, int* __restrict__ bbase,
                        int* __restrict__ bcursor, int* __restrict__ rowptr) {
    __shared__ int sdat[256];
    int t = threadIdx.x, run = 0;
    for (int c = 0; c < 5; ++c) {
        int i = c * 256 + t;
        int v = (i < NBUCK) ? bcnt[i] : 0;
        sdat[t] = v; __syncthreads();
        for (int off = 1; off < 256; off <<= 1) {
            int u = (t >= off) ? sdat[t - off] : 0;
            __syncthreads();
            sdat[t] += u;
            __syncthreads();
        }
        if (i < NBUCK) { int b = run + sdat[t] - v; bbase[i] = b; bcursor[i] = b; }
        run += sdat[255];
        __syncthreads();
    }
    if (t == 0) { bbase[NBUCK] = N_EDGES; rowptr[N_NODES] = N_EDGES; }
}

__global__ void k_bfill(const int* __restrict__ ei, int* __restrict__ bcursor,
                        int* __restrict__ ebuf) {
    int e = blockIdx.x * blockDim.x + threadIdx.x;
    if (e < N_EDGES) {
        int src = ei[e], dst = ei[N_EDGES + e];
        int p = atomicAdd(&bcursor[dst >> 6], 1);
        ebuf[p] = src | ((dst & 63) << 20);   // bucket region fills front-to-back
    }
}

// one block per bucket: per-node counts -> rowptr, then local scatter into col
__global__ __launch_bounds__(256) void k_bcsr(const int* __restrict__ ebuf,
        const int* __restrict__ bbase, int* __restrict__ rowptr,
        int* __restrict__ col) {
    __shared__ int cnt[64];
    __shared__ int cur[64];
    int b = blockIdx.x, t = threadIdx.x;
    int s = bbase[b], e = bbase[b + 1];
    if (t < 64) cnt[t] = 0;
    __syncthreads();
    for (int i = s + t; i < e; i += 256) atomicAdd(&cnt[ebuf[i] >> 20], 1);
    __syncthreads();
    if (t < 64) {
        int v = cnt[t];
        int inc = v;
        for (int off = 1; off < 64; off <<= 1) {
            int u = __shfl_up(inc, off);
            if (t >= off) inc += u;
        }
        int base = s + inc - v;     // exclusive
        rowptr[b * 64 + t] = base;
        cur[t] = base;
    }
    __syncthreads();
    for (int i = s + t; i < e; i += 256) {
        int pk = ebuf[i];
        int p = atomicAdd(&cur[pk >> 20], 1);
        col[p] = pk & 0xFFFFF;      // writes confined to ~4KB L2-hot region
    }
}

// ---------- weight pre-transpose: wcat[layer][k][n], k<64: w_rel[n][k], k>=64: w_root[n][k-64]
__global__ void k_prep(const float* __restrict__ wr1, const float* __restrict__ wo1,
                       const float* __restrict__ wr2, const float* __restrict__ wo2,
                       const float* __restrict__ wr3, const float* __restrict__ wo3,
                       float* __restrict__ wcat) {
    int idx = blockIdx.x * blockDim.x + threadIdx.x;
    if (idx >= 3 * 8192) return;
    int l = idx / 8192, r = idx % 8192, k = r / 64, n = r % 64;
    const float* wr = (l == 0) ? wr1 : (l == 1) ? wr2 : wr3;
    const float* wo = (l == 0) ? wo1 : (l == 1) ? wo2 : wo3;
    wcat[idx] = (k < 64) ? wr[n * 64 + k] : wo[n * 64 + (k - 64)];
}

// ---------- aggregation: one wave per node, lane = channel ----------
__global__ __launch_bounds__(256) void k_gather(const float* __restrict__ X,
        const int* __restrict__ rowptr, const int* __restrict__ col,
        float* __restrict__ agg) {
    int wave = threadIdx.x >> 6, lane = threadIdx.x & 63;
    int node = blockIdx.x * 4 + wave;
    if (node >= N_NODES) return;
    int start = rowptr[node], end = rowptr[node + 1];
    float a0 = 0.f, a1 = 0.f, a2 = 0.f, a3 = 0.f;
    int e = start;
    for (; e + 4 <= end; e += 4) {
        int s0 = col[e], s1 = col[e + 1], s2 = col[e + 2], s3 = col[e + 3];
        a0 += X[(size_t)s0 * 64 + lane];
        a1 += X[(size_t)s1 * 64 + lane];
        a2 += X[(size_t)s2 * 64 + lane];
        a3 += X[(size_t)s3 * 64 + lane];
    }
    for (; e < end; ++e) a0 += X[(size_t)col[e] * 64 + lane];
    agg[(size_t)node * 64 + lane] = (a0 + a1) + (a2 + a3);
}

// ---------- fused linear: out = act(AGG@WrelT + X@WrootT + b) ----------
__global__ __launch_bounds__(256) void k_linear(const float* __restrict__ agg,
        const float* __restrict__ xin, const float* __restrict__ wcat,
        const float* __restrict__ bias, float* __restrict__ out, int relu) {
    __shared__ __align__(16) float sA[64 * 68];    // k-major, padded
    __shared__ __align__(16) float sB[128 * 64];   // k-major, pre-transposed in ws
    __shared__ float sBias[64];
    int t = threadIdx.x;
    int m0 = blockIdx.x * 64;
    for (int i = t; i < 8192; i += 256) sB[i] = wcat[i];
    if (t < 64) sBias[t] = bias[t];
    float acc[4][4] = {{0.f}};
    int tn = (t & 15) * 4;       // n-offset
    int tm = (t >> 4) * 4;       // m-offset
    for (int pass = 0; pass < 2; ++pass) {
        const float* src = pass ? xin : agg;
        __syncthreads();
        for (int r = 0; r < 4; ++r) {
            int f = r * 256 + t;
            int c4 = f & 15, m = f >> 4;
            float4 v = *(const float4*)&src[(size_t)(m0 + m) * 64 + c4 * 4];
            sA[(c4 * 4 + 0) * 68 + m] = v.x;
            sA[(c4 * 4 + 1) * 68 + m] = v.y;
            sA[(c4 * 4 + 2) * 68 + m] = v.z;
            sA[(c4 * 4 + 3) * 68 + m] = v.w;
        }
        __syncthreads();
        const float* Bp = sB + pass * 4096;
#pragma unroll 4
        for (int k = 0; k < 64; ++k) {
            float4 a = *(const float4*)&sA[k * 68 + tm];
            float4 b = *(const float4*)&Bp[k * 64 + tn];
            acc[0][0] += a.x * b.x; acc[0][1] += a.x * b.y; acc[0][2] += a.x * b.z; acc[0][3] += a.x * b.w;
            acc[1][0] += a.y * b.x; acc[1][1] += a.y * b.y; acc[1][2] += a.y * b.z; acc[1][3] += a.y * b.w;
            acc[2][0] += a.z * b.x; acc[2][1] += a.z * b.y; acc[2][2] += a.z * b.z; acc[2][3] += a.z * b.w;
            acc[3][0] += a.w * b.x; acc[3][1] += a.w * b.y; acc[3][2] += a.w * b.z; acc[3][3] += a.w * b.w;
        }
    }
#pragma unroll
    for (int i = 0; i < 4; ++i) {
        float4 v;
        v.x = acc[i][0] + sBias[tn + 0];
        v.y = acc[i][1] + sBias[tn + 1];
        v.z = acc[i][2] + sBias[tn + 2];
        v.w = acc[i][3] + sBias[tn + 3];
        if (relu) {
            v.x = fmaxf(v.x, 0.f); v.y = fmaxf(v.y, 0.f);
            v.z = fmaxf(v.z, 0.f); v.w = fmaxf(v.w, 0.f);
        }
        *(float4*)&out[(size_t)(m0 + tm + i) * 64 + tn] = v;
    }
}

// ---------- mean pool over sorted batch ids ----------
static __device__ __forceinline__ int lowerb(const int* a, int n, int key) {
    int lo = 0, hi = n;
    while (lo < hi) { int mid = (lo + hi) >> 1; if (a[mid] < key) lo = mid + 1; else hi = mid; }
    return lo;
}

__global__ __launch_bounds__(256) void k_pool(const float* __restrict__ h,
        const int* __restrict__ batch, float* __restrict__ pooled) {
    __shared__ float sp[4][64];
    int g = blockIdx.x;
    int t = threadIdx.x, wave = t >> 6, lane = t & 63;
    int start = lowerb(batch, N_NODES, g);
    int end   = lowerb(batch, N_NODES, g + 1);
    float acc = 0.f;
    for (int i = start + wave; i < end; i += 4) acc += h[(size_t)i * 64 + lane];
    sp[wave][lane] = acc;
    __syncthreads();
    if (t < 64) {
        float v = sp[0][t] + sp[1][t] + sp[2][t] + sp[3][t];
        int cnt = end - start;
        v /= (float)((cnt > 0) ? cnt : 1);
        pooled[g * 64 + t] = v;
    }
}

__global__ void k_head(const float* __restrict__ pooled, const float* __restrict__ wlin,
                       const float* __restrict__ blin, float* __restrict__ out) {
    int g = blockIdx.x, lane = threadIdx.x;
    float p = pooled[g * 64 + lane];
    float myout = 0.f;
    for (int cls = 0; cls < NCLS; ++cls) {
        float v = p * wlin[cls * 64 + lane];
        for (int off = 32; off > 0; off >>= 1) v += __shfl_xor(v, off);
        if (lane == cls) myout = v + blin[cls];
    }
    if (lane < NCLS) out[g * NCLS + lane] = myout;
}

extern "C" void kernel_launch(void* const* d_in, const int* in_sizes, int n_in,
                              void* d_out, int out_size, void* d_ws, size_t ws_size,
                              hipStream_t stream) {
    const float* x     = (const float*)d_in[0];
    const int*   ei    = (const int*)d_in[1];
    const int*   batch = (const int*)d_in[2];
    const float* wr1 = (const float*)d_in[3];
    const float* b1  = (const float*)d_in[4];
    const float* wo1 = (const float*)d_in[5];
    const float* wr2 = (const float*)d_in[6];
    const float* b2  = (const float*)d_in[7];
    const float* wo2 = (const float*)d_in[8];
    const float* wr3 = (const float*)d_in[9];
    const float* b3  = (const float*)d_in[10];
    const float* wo3 = (const float*)d_in[11];
    const float* wlin = (const float*)d_in[12];
    const float* blin = (const float*)d_in[13];
    float* out = (float*)d_out;

    char* p = (char*)d_ws;
    auto alloc = [&](size_t bytes) { char* r = p; p += (bytes + 255) & ~(size_t)255; return r; };
    int*   rowptr = (int*)alloc((N_NODES + 1) * sizeof(int));
    int*   bcnt   = (int*)alloc((NBUCK + 1) * sizeof(int));
    int*   bbase  = (int*)alloc((NBUCK + 1) * sizeof(int));
    int*   bcursor= (int*)alloc((NBUCK + 1) * sizeof(int));
    int*   ebuf   = (int*)alloc((size_t)N_EDGES * sizeof(int));
    int*   col    = (int*)alloc((size_t)N_EDGES * sizeof(int));
    float* wcat   = (float*)alloc(3 * 8192 * sizeof(float));
    float* agg    = (float*)alloc((size_t)N_NODES * 64 * sizeof(float));
    float* hA     = (float*)alloc((size_t)N_NODES * 64 * sizeof(float));
    float* hB     = (float*)alloc((size_t)N_NODES * 64 * sizeof(float));
    float* pooled = (float*)alloc((size_t)N_GRAPHS * 64 * sizeof(float));

    // CSR build: bucket-count -> scan -> bucket-fill -> per-bucket CSR
    hipMemsetAsync(bcnt, 0, NBUCK * sizeof(int), stream);
    k_bcount<<<N_EDGES / 256, 256, 0, stream>>>(ei, bcnt);
    k_scanb <<<1, 256, 0, stream>>>(bcnt, bbase, bcursor, rowptr);
    k_bfill <<<N_EDGES / 256, 256, 0, stream>>>(ei, bcursor, ebuf);
    k_bcsr  <<<NBUCK, 256, 0, stream>>>(ebuf, bbase, rowptr, col);
    k_prep  <<<(3 * 8192 + 255) / 256, 256, 0, stream>>>(wr1, wo1, wr2, wo2, wr3, wo3, wcat);

    // layer 1: x -> hA (relu)
    k_gather<<<N_NODES / 4, 256, 0, stream>>>(x, rowptr, col, agg);
    k_linear<<<N_NODES / 64, 256, 0, stream>>>(agg, x, wcat, b1, hA, 1);
    // layer 2: hA -> hB (relu)
    k_gather<<<N_NODES / 4, 256, 0, stream>>>(hA, rowptr, col, agg);
    k_linear<<<N_NODES / 64, 256, 0, stream>>>(agg, hA, wcat + 8192, b2, hB, 1);
    // layer 3: hB -> hA (no relu)
    k_gather<<<N_NODES / 4, 256, 0, stream>>>(hB, rowptr, col, agg);
    k_linear<<<N_NODES / 64, 256, 0, stream>>>(agg, hB, wcat + 16384, b3, hA, 0);

    // pool + head
    k_pool<<<N_GRAPHS, 256, 0, stream>>>(hA, batch, pooled);
    k_head<<<N_GRAPHS, 64, 0, stream>>>(pooled, wlin, blin, out);
}

// Round 4
// 405.772 us; speedup vs baseline: 2.0185x; 2.0185x over previous
//
#include <hip/hip_runtime.h>

#define N_NODES  80000
#define N_EDGES  1280000
#define N_GRAPHS 512
#define DIM      64
#define NCLS     10

#define ETILE    8192
#define NTILE    157      // ceil(N_EDGES / ETILE)
#define NCB      157      // ceil(N_NODES / 512) coarse buckets of 512 nodes
#define CBPAD    160

// ---------- Pass A: per-tile histogram over coarse buckets (no global atomics)
__global__ __launch_bounds__(256) void k_hist(const int* __restrict__ ei,
                                              int* __restrict__ hmat) {
    __shared__ int hist[NCB];
    int tile = blockIdx.x, t = threadIdx.x;
    for (int i = t; i < NCB; i += 256) hist[i] = 0;
    __syncthreads();
    int base = tile * ETILE;
    int end = base + ETILE; if (end > N_EDGES) end = N_EDGES;
    for (int i = base + t; i < end; i += 256)
        atomicAdd(&hist[ei[N_EDGES + i] >> 9], 1);
    __syncthreads();
    for (int i = t; i < NCB; i += 256) hmat[tile * CBPAD + i] = hist[i];
}

// ---------- Pass B1: per-bucket scan across tiles -> within-bucket offsets
__global__ __launch_bounds__(256) void k_scanT(const int* __restrict__ hmat,
        int* __restrict__ obase, int* __restrict__ btot) {
    __shared__ int sa[256], sb[256];
    int b = blockIdx.x, t = threadIdx.x;
    int v = (t < NTILE) ? hmat[t * CBPAD + b] : 0;
    sa[t] = v; __syncthreads();
    int* sp = sa; int* dp = sb;
    for (int off = 1; off < 256; off <<= 1) {
        dp[t] = sp[t] + ((t >= off) ? sp[t - off] : 0);
        __syncthreads();
        int* tmp = sp; sp = dp; dp = tmp;
    }
    int incl = sp[t];
    if (t < NTILE) obase[t * CBPAD + b] = incl - v;
    if (t == NTILE - 1) btot[b] = incl;
}

// ---------- Pass B2: scan bucket totals -> bucket bases
__global__ __launch_bounds__(256) void k_scanB(const int* __restrict__ btot,
        int* __restrict__ bucketbase, int* __restrict__ rowptr) {
    __shared__ int sa[256], sb[256];
    int t = threadIdx.x;
    int v = (t < NCB) ? btot[t] : 0;
    sa[t] = v; __syncthreads();
    int* sp = sa; int* dp = sb;
    for (int off = 1; off < 256; off <<= 1) {
        dp[t] = sp[t] + ((t >= off) ? sp[t - off] : 0);
        __syncthreads();
        int* tmp = sp; sp = dp; dp = tmp;
    }
    int incl = sp[t];
    if (t < NCB) bucketbase[t] = incl - v;
    if (t == 0) { bucketbase[NCB] = N_EDGES; rowptr[N_NODES] = N_EDGES; }
}

// ---------- Pass C: scatter into bucket-sorted ebuf; each tile writes
// a private contiguous run per bucket (deterministic base, LDS cursor only)
__global__ __launch_bounds__(256) void k_scatter(const int* __restrict__ ei,
        const int* __restrict__ obase, const int* __restrict__ bucketbase,
        int* __restrict__ ebuf) {
    __shared__ int cur[NCB];
    int tile = blockIdx.x, t = threadIdx.x;
    for (int i = t; i < NCB; i += 256)
        cur[i] = bucketbase[i] + obase[tile * CBPAD + i];
    __syncthreads();
    int base = tile * ETILE;
    int end = base + ETILE; if (end > N_EDGES) end = N_EDGES;
    for (int i = base + t; i < end; i += 256) {
        int s = ei[i], d = ei[N_EDGES + i];
        int p = atomicAdd(&cur[d >> 9], 1);
        ebuf[p] = s | ((d & 511) << 17);   // src:17 bits, local dst:9 bits
    }
}

// ---------- Pass D: per-bucket node-level CSR, all in LDS + 32KB col region
__global__ __launch_bounds__(256) void k_csr(const int* __restrict__ ebuf,
        const int* __restrict__ bucketbase, int* __restrict__ rowptr,
        int* __restrict__ col) {
    __shared__ int cnt[512];
    __shared__ int sa[512], sb[512];
    __shared__ int cur[512];
    int b = blockIdx.x, t = threadIdx.x;
    int s = bucketbase[b], e = bucketbase[b + 1];
    cnt[t] = 0; cnt[t + 256] = 0;
    __syncthreads();
    for (int i = s + t; i < e; i += 256) atomicAdd(&cnt[ebuf[i] >> 17], 1);
    __syncthreads();
    sa[t] = cnt[t]; sa[t + 256] = cnt[t + 256];
    __syncthreads();
    int* sp = sa; int* dp = sb;
    for (int off = 1; off < 512; off <<= 1) {
        int i1 = t + 256;
        int v0 = sp[t]  + ((t  >= off) ? sp[t  - off] : 0);
        int v1 = sp[i1] + ((i1 >= off) ? sp[i1 - off] : 0);
        __syncthreads();
        dp[t] = v0; dp[i1] = v1;
        __syncthreads();
        int* tmp = sp; sp = dp; dp = tmp;
    }
    int node0 = b * 512;
    int base0 = s + sp[t] - cnt[t];
    int base1 = s + sp[t + 256] - cnt[t + 256];
    cur[t] = base0; cur[t + 256] = base1;
    if (node0 + t < N_NODES)       rowptr[node0 + t] = base0;
    if (node0 + t + 256 < N_NODES) rowptr[node0 + t + 256] = base1;
    __syncthreads();
    for (int i = s + t; i < e; i += 256) {
        int pk = ebuf[i];
        int p = atomicAdd(&cur[pk >> 17], 1);
        col[p] = pk & 0x1FFFF;
    }
}

// ---------- weight pre-transpose: wcat[layer][k][n]
__global__ void k_prep(const float* __restrict__ wr1, const float* __restrict__ wo1,
                       const float* __restrict__ wr2, const float* __restrict__ wo2,
                       const float* __restrict__ wr3, const float* __restrict__ wo3,
                       float* __restrict__ wcat) {
    int idx = blockIdx.x * blockDim.x + threadIdx.x;
    if (idx >= 3 * 8192) return;
    int l = idx / 8192, r = idx % 8192, k = r / 64, n = r % 64;
    const float* wr = (l == 0) ? wr1 : (l == 1) ? wr2 : wr3;
    const float* wo = (l == 0) ? wo1 : (l == 1) ? wo2 : wo3;
    wcat[idx] = (k < 64) ? wr[n * 64 + k] : wo[n * 64 + (k - 64)];
}

// ---------- aggregation: one wave per node, lane = channel ----------
__global__ __launch_bounds__(256) void k_gather(const float* __restrict__ X,
        const int* __restrict__ rowptr, const int* __restrict__ col,
        float* __restrict__ agg) {
    int wave = threadIdx.x >> 6, lane = threadIdx.x & 63;
    int node = blockIdx.x * 4 + wave;
    if (node >= N_NODES) return;
    int start = rowptr[node], end = rowptr[node + 1];
    float a0 = 0.f, a1 = 0.f, a2 = 0.f, a3 = 0.f;
    int e = start;
    for (; e + 4 <= end; e += 4) {
        int s0 = col[e], s1 = col[e + 1], s2 = col[e + 2], s3 = col[e + 3];
        a0 += X[(size_t)s0 * 64 + lane];
        a1 += X[(size_t)s1 * 64 + lane];
        a2 += X[(size_t)s2 * 64 + lane];
        a3 += X[(size_t)s3 * 64 + lane];
    }
    for (; e < end; ++e) a0 += X[(size_t)col[e] * 64 + lane];
    agg[(size_t)node * 64 + lane] = (a0 + a1) + (a2 + a3);
}

// ---------- fused linear: out = act(AGG@WrelT + X@WrootT + b) ----------
__global__ __launch_bounds__(256) void k_linear(const float* __restrict__ agg,
        const float* __restrict__ xin, const float* __restrict__ wcat,
        const float* __restrict__ bias, float* __restrict__ out, int relu) {
    __shared__ __align__(16) float sA[64 * 68];
    __shared__ __align__(16) float sB[128 * 64];
    __shared__ float sBias[64];
    int t = threadIdx.x;
    int m0 = blockIdx.x * 64;
    for (int i = t; i < 8192; i += 256) sB[i] = wcat[i];
    if (t < 64) sBias[t] = bias[t];
    float acc[4][4] = {{0.f}};
    int tn = (t & 15) * 4;
    int tm = (t >> 4) * 4;
    for (int pass = 0; pass < 2; ++pass) {
        const float* src = pass ? xin : agg;
        __syncthreads();
        for (int r = 0; r < 4; ++r) {
            int f = r * 256 + t;
            int c4 = f & 15, m = f >> 4;
            float4 v = *(const float4*)&src[(size_t)(m0 + m) * 64 + c4 * 4];
            sA[(c4 * 4 + 0) * 68 + m] = v.x;
            sA[(c4 * 4 + 1) * 68 + m] = v.y;
            sA[(c4 * 4 + 2) * 68 + m] = v.z;
            sA[(c4 * 4 + 3) * 68 + m] = v.w;
        }
        __syncthreads();
        const float* Bp = sB + pass * 4096;
#pragma unroll 4
        for (int k = 0; k < 64; ++k) {
            float4 a = *(const float4*)&sA[k * 68 + tm];
            float4 b = *(const float4*)&Bp[k * 64 + tn];
            acc[0][0] += a.x * b.x; acc[0][1] += a.x * b.y; acc[0][2] += a.x * b.z; acc[0][3] += a.x * b.w;
            acc[1][0] += a.y * b.x; acc[1][1] += a.y * b.y; acc[1][2] += a.y * b.z; acc[1][3] += a.y * b.w;
            acc[2][0] += a.z * b.x; acc[2][1] += a.z * b.y; acc[2][2] += a.z * b.z; acc[2][3] += a.z * b.w;
            acc[3][0] += a.w * b.x; acc[3][1] += a.w * b.y; acc[3][2] += a.w * b.z; acc[3][3] += a.w * b.w;
        }
    }
#pragma unroll
    for (int i = 0; i < 4; ++i) {
        float4 v;
        v.x = acc[i][0] + sBias[tn + 0];
        v.y = acc[i][1] + sBias[tn + 1];
        v.z = acc[i][2] + sBias[tn + 2];
        v.w = acc[i][3] + sBias[tn + 3];
        if (relu) {
            v.x = fmaxf(v.x, 0.f); v.y = fmaxf(v.y, 0.f);
            v.z = fmaxf(v.z, 0.f); v.w = fmaxf(v.w, 0.f);
        }
        *(float4*)&out[(size_t)(m0 + tm + i) * 64 + tn] = v;
    }
}

// ---------- mean pool over sorted batch ids ----------
static __device__ __forceinline__ int lowerb(const int* a, int n, int key) {
    int lo = 0, hi = n;
    while (lo < hi) { int mid = (lo + hi) >> 1; if (a[mid] < key) lo = mid + 1; else hi = mid; }
    return lo;
}

__global__ __launch_bounds__(256) void k_pool(const float* __restrict__ h,
        const int* __restrict__ batch, float* __restrict__ pooled) {
    __shared__ float sp[4][64];
    int g = blockIdx.x;
    int t = threadIdx.x, wave = t >> 6, lane = t & 63;
    int start = lowerb(batch, N_NODES, g);
    int end   = lowerb(batch, N_NODES, g + 1);
    float acc = 0.f;
    for (int i = start + wave; i < end; i += 4) acc += h[(size_t)i * 64 + lane];
    sp[wave][lane] = acc;
    __syncthreads();
    if (t < 64) {
        float v = sp[0][t] + sp[1][t] + sp[2][t] + sp[3][t];
        int cnt = end - start;
        v /= (float)((cnt > 0) ? cnt : 1);
        pooled[g * 64 + t] = v;
    }
}

__global__ void k_head(const float* __restrict__ pooled, const float* __restrict__ wlin,
                       const float* __restrict__ blin, float* __restrict__ out) {
    int g = blockIdx.x, lane = threadIdx.x;
    float p = pooled[g * 64 + lane];
    float myout = 0.f;
    for (int cls = 0; cls < NCLS; ++cls) {
        float v = p * wlin[cls * 64 + lane];
        for (int off = 32; off > 0; off >>= 1) v += __shfl_xor(v, off);
        if (lane == cls) myout = v + blin[cls];
    }
    if (lane < NCLS) out[g * NCLS + lane] = myout;
}

extern "C" void kernel_launch(void* const* d_in, const int* in_sizes, int n_in,
                              void* d_out, int out_size, void* d_ws, size_t ws_size,
                              hipStream_t stream) {
    const float* x     = (const float*)d_in[0];
    const int*   ei    = (const int*)d_in[1];
    const int*   batch = (const int*)d_in[2];
    const float* wr1 = (const float*)d_in[3];
    const float* b1  = (const float*)d_in[4];
    const float* wo1 = (const float*)d_in[5];
    const float* wr2 = (const float*)d_in[6];
    const float* b2  = (const float*)d_in[7];
    const float* wo2 = (const float*)d_in[8];
    const float* wr3 = (const float*)d_in[9];
    const float* b3  = (const float*)d_in[10];
    const float* wo3 = (const float*)d_in[11];
    const float* wlin = (const float*)d_in[12];
    const float* blin = (const float*)d_in[13];
    float* out = (float*)d_out;

    char* p = (char*)d_ws;
    auto alloc = [&](size_t bytes) { char* r = p; p += (bytes + 255) & ~(size_t)255; return r; };
    int*   rowptr  = (int*)alloc((N_NODES + 1) * sizeof(int));
    int*   hmat    = (int*)alloc((size_t)NTILE * CBPAD * sizeof(int));
    int*   obase   = (int*)alloc((size_t)NTILE * CBPAD * sizeof(int));
    int*   btot    = (int*)alloc(CBPAD * sizeof(int));
    int*   bucketbase = (int*)alloc((NCB + 1) * sizeof(int));
    int*   ebuf    = (int*)alloc((size_t)N_EDGES * sizeof(int));
    int*   col     = (int*)alloc((size_t)N_EDGES * sizeof(int));
    float* wcat    = (float*)alloc(3 * 8192 * sizeof(float));
    float* agg     = (float*)alloc((size_t)N_NODES * 64 * sizeof(float));
    float* hA      = (float*)alloc((size_t)N_NODES * 64 * sizeof(float));
    float* hB      = (float*)alloc((size_t)N_NODES * 64 * sizeof(float));
    float* pooled  = (float*)alloc((size_t)N_GRAPHS * 64 * sizeof(float));

    // CSR build: deterministic two-level counting sort, zero global atomics
    k_hist   <<<NTILE, 256, 0, stream>>>(ei, hmat);
    k_scanT  <<<NCB,   256, 0, stream>>>(hmat, obase, btot);
    k_scanB  <<<1,     256, 0, stream>>>(btot, bucketbase, rowptr);
    k_scatter<<<NTILE, 256, 0, stream>>>(ei, obase, bucketbase, ebuf);
    k_csr    <<<NCB,   256, 0, stream>>>(ebuf, bucketbase, rowptr, col);
    k_prep   <<<(3 * 8192 + 255) / 256, 256, 0, stream>>>(wr1, wo1, wr2, wo2, wr3, wo3, wcat);

    // layer 1: x -> hA (relu)
    k_gather<<<N_NODES / 4, 256, 0, stream>>>(x, rowptr, col, agg);
    k_linear<<<N_NODES / 64, 256, 0, stream>>>(agg, x, wcat, b1, hA, 1);
    // layer 2: hA -> hB (relu)
    k_gather<<<N_NODES / 4, 256, 0, stream>>>(hA, rowptr, col, agg);
    k_linear<<<N_NODES / 64, 256, 0, stream>>>(agg, hA, wcat + 8192, b2, hB, 1);
    // layer 3: hB -> hA (no relu)
    k_gather<<<N_NODES / 4, 256, 0, stream>>>(hB, rowptr, col, agg);
    k_linear<<<N_NODES / 64, 256, 0, stream>>>(agg, hB, wcat + 16384, b3, hA, 0);

    // pool + head
    k_pool<<<N_GRAPHS, 256, 0, stream>>>(hA, batch, pooled);
    k_head<<<N_GRAPHS, 64, 0, stream>>>(pooled, wlin, blin, out);
}